// Round 6
// baseline (205.662 us; speedup 1.0000x reference)
//
#include <hip/hip_runtime.h>
#include <hip/hip_bf16.h>
#include <stdint.h>

// SelfAttention: B=4, C=64, H=W=64 -> N=4096 tokens, d=64.
// R5 passed (absmax 0.031) but attn occupancy was 11% (1 block/CU, grid=256).
// R6: (1) attention KV-split (dynamic SPLIT from ws_size) + combine pass;
//     (2) K/V read DIRECT from global (L2-resident, 1MB/batch) -> no K/V LDS,
//         no __syncthreads in the KV loop, LDS 41KB->8.4KB;
//     (3) qkv_proj: 32 tokens/block (2x grid), LDS pad 38 breaks 4-way conflict.

#define DIM  64
#define NTOK 4096
#define NB   4

typedef float  f32x4 __attribute__((ext_vector_type(4)));
typedef float  f32x2 __attribute__((ext_vector_type(2)));
typedef __bf16 bf16x8 __attribute__((ext_vector_type(8)));
typedef _Float16 f16x8 __attribute__((ext_vector_type(8)));
typedef unsigned short u16x8 __attribute__((ext_vector_type(8)));
typedef unsigned short u16x4 __attribute__((ext_vector_type(4)));

__device__ __forceinline__ unsigned short f2h(float f) {
  return __builtin_bit_cast(unsigned short, (_Float16)f);
}
__device__ __forceinline__ float h2f(unsigned short u) {
  return (float)__builtin_bit_cast(_Float16, u);
}

// ---------------- QKV projection (f32-accurate via bf16 hi/lo 3-term MFMA) ----------------
// grid = NB * (NTOK/32), block = 256 (4 waves). Block: 32 tokens; wave w: out chans 16w..+15.
// Outputs: Qg,Kg = [b][n][64] fp16, Vg = [b][c][n] fp16.
__global__ __launch_bounds__(256) void qkv_proj(
    const float* __restrict__ x,
    const float* __restrict__ Wq, const float* __restrict__ bq,
    const float* __restrict__ Wk, const float* __restrict__ bk,
    const float* __restrict__ Wv, const float* __restrict__ bv,
    unsigned short* __restrict__ Qg, unsigned short* __restrict__ Kg,
    unsigned short* __restrict__ Vg)
{
  __shared__ __align__(16) float xs[64][38];   // [c][n]; stride 38 -> lg-read conflict 2-way
  const int tid = threadIdx.x;
  const int b  = blockIdx.x >> 7;
  const int n0 = (blockIdx.x & 127) << 5;
  const float* xb = x + (size_t)b * DIM * NTOK;

  for (int u = tid; u < 64 * 8; u += 256) {
    int c = u >> 3, q = u & 7;
    f32x4 v = *(const f32x4*)(xb + (size_t)c * NTOK + n0 + q * 4);
    *(f32x2*)&xs[c][q * 4]     = (f32x2){v[0], v[1]};
    *(f32x2*)&xs[c][q * 4 + 2] = (f32x2){v[2], v[3]};
  }
  __syncthreads();

  const int w = tid >> 6, l = tid & 63;
  const int lr = l & 15, lg = l >> 4;
  const int o0 = w << 4;

  // x^T hi/lo fragments: A-frag rows n (Q/K) == B-frag cols n (V). c = ks*32 + lg*8 + e.
  bf16x8 xh[2][2], xl[2][2];
  #pragma unroll
  for (int ns = 0; ns < 2; ns++) {
    #pragma unroll
    for (int ks = 0; ks < 2; ks++) {
      u16x8 uh, ul;
      #pragma unroll
      for (int e = 0; e < 8; e++) {
        float v = xs[ks * 32 + lg * 8 + e][ns * 16 + lr];
        __bf16 h = (__bf16)v;
        uh[e] = __builtin_bit_cast(unsigned short, h);
        ul[e] = __builtin_bit_cast(unsigned short, (__bf16)(v - (float)h));
      }
      xh[ns][ks] = __builtin_bit_cast(bf16x8, uh);
      xl[ns][ks] = __builtin_bit_cast(bf16x8, ul);
    }
  }

  // W hi/lo fragments: row o0+lr, 8 contiguous c. B-frag (W^T) for Q/K, A-frag for V.
  bf16x8 wh[3][2], wl[3][2];
  const float* Wm[3] = {Wq, Wk, Wv};
  #pragma unroll
  for (int m = 0; m < 3; m++) {
    #pragma unroll
    for (int ks = 0; ks < 2; ks++) {
      const float* p = Wm[m] + (o0 + lr) * DIM + ks * 32 + lg * 8;
      u16x8 uh, ul;
      #pragma unroll
      for (int e = 0; e < 8; e++) {
        float v = p[e];
        __bf16 h = (__bf16)v;
        uh[e] = __builtin_bit_cast(unsigned short, h);
        ul[e] = __builtin_bit_cast(unsigned short, (__bf16)(v - (float)h));
      }
      wh[m][ks] = __builtin_bit_cast(bf16x8, uh);
      wl[m][ks] = __builtin_bit_cast(bf16x8, ul);
    }
  }

  const float bqv = bq[o0 + lr], bkv = bk[o0 + lr];
  float bvv[4];
  #pragma unroll
  for (int r = 0; r < 4; r++) bvv[r] = bv[o0 + lg * 4 + r];

  #pragma unroll
  for (int ns = 0; ns < 2; ns++) {
    f32x4 aq = {bqv, bqv, bqv, bqv};
    f32x4 ak = {bkv, bkv, bkv, bkv};
    f32x4 av = {bvv[0], bvv[1], bvv[2], bvv[3]};
    #pragma unroll
    for (int ks = 0; ks < 2; ks++) {
      // (xh+xl)(wh+wl) ~= xh*wh + xh*wl + xl*wh  (dropped xl*wl ~ 2^-16 relative)
      aq = __builtin_amdgcn_mfma_f32_16x16x32_bf16(xh[ns][ks], wh[0][ks], aq, 0, 0, 0);
      aq = __builtin_amdgcn_mfma_f32_16x16x32_bf16(xh[ns][ks], wl[0][ks], aq, 0, 0, 0);
      aq = __builtin_amdgcn_mfma_f32_16x16x32_bf16(xl[ns][ks], wh[0][ks], aq, 0, 0, 0);
      ak = __builtin_amdgcn_mfma_f32_16x16x32_bf16(xh[ns][ks], wh[1][ks], ak, 0, 0, 0);
      ak = __builtin_amdgcn_mfma_f32_16x16x32_bf16(xh[ns][ks], wl[1][ks], ak, 0, 0, 0);
      ak = __builtin_amdgcn_mfma_f32_16x16x32_bf16(xl[ns][ks], wh[1][ks], ak, 0, 0, 0);
      av = __builtin_amdgcn_mfma_f32_16x16x32_bf16(wh[2][ks], xh[ns][ks], av, 0, 0, 0);
      av = __builtin_amdgcn_mfma_f32_16x16x32_bf16(wl[2][ks], xh[ns][ks], av, 0, 0, 0);
      av = __builtin_amdgcn_mfma_f32_16x16x32_bf16(wh[2][ks], xl[ns][ks], av, 0, 0, 0);
    }
    // Q/K tiles: D[row=n][col=o]; lane: o = o0+lr, n = n0+ns*16+4*lg+r
    #pragma unroll
    for (int r = 0; r < 4; r++) {
      int n = n0 + ns * 16 + lg * 4 + r;
      size_t base = ((size_t)b * NTOK + n) * DIM + o0 + lr;
      Qg[base] = f2h(aq[r]);
      Kg[base] = f2h(ak[r]);
    }
    // V tiles: D[row=o][col=n]; lane: n = n0+ns*16+lr, o = o0+4*lg+r
    #pragma unroll
    for (int r = 0; r < 4; r++) {
      int n = n0 + ns * 16 + lr;
      int o = o0 + lg * 4 + r;
      Vg[((size_t)b * DIM + o) * NTOK + n] = f2h(av[r]);
    }
  }
}

// ---------------- Flash attention, KV-split pass ----------------
// grid = NB*64*nsplit, block 256 (4 waves), wave w owns Q rows i0+16w..+15.
// K/V read directly from global (L2-resident); no block-wide barriers in KV loop.
// direct=1 (nsplit==1, no ws room): normalize + write out. Else store partial O,m,l.
__global__ __launch_bounds__(256, 4) void attn_part(
    const unsigned short* __restrict__ Qg, const unsigned short* __restrict__ Kg,
    const unsigned short* __restrict__ Vg,
    float* __restrict__ Op, float* __restrict__ Ml, float* __restrict__ out,
    int nsplit, int tiles, int direct)
{
  __shared__ __align__(16) unsigned short Pk[4 * 1056]; // per-wave P: [i_hi:4][j:66pad][i_lo:4]

  const int tid = threadIdx.x;
  const int w = tid >> 6, l = tid & 63;
  const int lr = l & 15, lg = l >> 4;
  const int s  = blockIdx.x % nsplit;
  const int bi = blockIdx.x / nsplit;
  const int b  = bi >> 6;
  const int i0 = (bi & 63) << 6;

  const unsigned short* Kb = Kg + (size_t)b * NTOK * DIM;   // [j][c]
  const unsigned short* Vb = Vg + (size_t)b * DIM * NTOK;   // [c][j]

  // Q fragments (registers, reused for all tiles)
  f16x8 qf[2];
  {
    const unsigned short* qp = Qg + ((size_t)b * NTOK + i0 + w * 16 + lr) * DIM;
    qf[0] = __builtin_bit_cast(f16x8, *(const u16x8*)(qp + lg * 8));
    qf[1] = __builtin_bit_cast(f16x8, *(const u16x8*)(qp + 32 + lg * 8));
  }

  float m[4], ls[4];
  f32x4 accO[4];
  #pragma unroll
  for (int r = 0; r < 4; r++) { m[r] = -3.0e38f; ls[r] = 0.f; }
  #pragma unroll
  for (int ct = 0; ct < 4; ct++) accO[ct] = (f32x4){0.f, 0.f, 0.f, 0.f};

  const int t0 = s * tiles;
  for (int t = 0; t < tiles; t++) {
    const int j0 = (t0 + t) << 6;

    // ---- S = Q K^T  (4 j-subtiles x K=64); K-frag = contiguous u16x8 from global ----
    f32x4 S[4];
    #pragma unroll
    for (int jt = 0; jt < 4; jt++) {
      f32x4 s4 = {0.f, 0.f, 0.f, 0.f};
      #pragma unroll
      for (int ks = 0; ks < 2; ks++) {
        u16x8 kv = *(const u16x8*)(Kb + (size_t)(j0 + jt * 16 + lr) * DIM + ks * 32 + lg * 8);
        s4 = __builtin_amdgcn_mfma_f32_16x16x32_f16(qf[ks], __builtin_bit_cast(f16x8, kv), s4, 0, 0, 0);
      }
      S[jt] = s4;
    }

    // ---- online softmax (rows i = 4*lg + r; reduce over j = lanes lr 0..15) ----
    float mx[4], mn[4], sc[4], rs[4];
    #pragma unroll
    for (int r = 0; r < 4; r++)
      mx[r] = fmaxf(fmaxf(S[0][r], S[1][r]), fmaxf(S[2][r], S[3][r]));
    #pragma unroll
    for (int sh = 8; sh >= 1; sh >>= 1) {
      #pragma unroll
      for (int r = 0; r < 4; r++)
        mx[r] = fmaxf(mx[r], __shfl_xor(mx[r], sh));
    }
    #pragma unroll
    for (int r = 0; r < 4; r++) {
      mn[r] = fmaxf(m[r], mx[r]);
      sc[r] = __expf(m[r] - mn[r]);
      rs[r] = 0.f;
    }
    #pragma unroll
    for (int jt = 0; jt < 4; jt++) {
      u16x4 pb;
      #pragma unroll
      for (int r = 0; r < 4; r++) {
        unsigned short u = f2h(__expf(S[jt][r] - mn[r]));
        pb[r] = u;
        rs[r] += h2f(u);     // sum rounded P for numerator/denominator consistency
      }
      *(u16x4*)&Pk[w * 1056 + lg * 264 + (jt * 16 + lr) * 4] = pb;
    }
    #pragma unroll
    for (int sh = 8; sh >= 1; sh >>= 1) {
      #pragma unroll
      for (int r = 0; r < 4; r++)
        rs[r] += __shfl_xor(rs[r], sh);
    }
    #pragma unroll
    for (int r = 0; r < 4; r++) {
      ls[r] = ls[r] * sc[r] + rs[r];
      m[r] = mn[r];
    }
    #pragma unroll
    for (int ct = 0; ct < 4; ct++) {
      #pragma unroll
      for (int r = 0; r < 4; r++)
        accO[ct][r] *= sc[r];
    }

    // ---- O += P V  (V-frag = contiguous u16x8 from global) ----
    const int ihi = lr >> 2, ilo = lr & 3;
    #pragma unroll
    for (int ks = 0; ks < 2; ks++) {
      u16x8 pu;
      #pragma unroll
      for (int e = 0; e < 8; e++)
        pu[e] = Pk[w * 1056 + ihi * 264 + (ks * 32 + lg * 8 + e) * 4 + ilo];
      f16x8 pf = __builtin_bit_cast(f16x8, pu);
      #pragma unroll
      for (int ct = 0; ct < 4; ct++) {
        u16x8 vv = *(const u16x8*)(Vb + (size_t)(ct * 16 + lr) * NTOK + j0 + ks * 32 + lg * 8);
        accO[ct] = __builtin_amdgcn_mfma_f32_16x16x32_f16(pf, __builtin_bit_cast(f16x8, vv), accO[ct], 0, 0, 0);
      }
    }
    // no barrier: Pk is per-wave; K/V come from global
  }

  // lane holds cols c = ct*16+lr, rows i = w*16+lg*4+r (r contiguous in i)
  if (direct) {
    float rl[4];
    #pragma unroll
    for (int r = 0; r < 4; r++) rl[r] = 1.0f / ls[r];
    #pragma unroll
    for (int ct = 0; ct < 4; ct++) {
      f32x4 o;
      #pragma unroll
      for (int r = 0; r < 4; r++) o[r] = accO[ct][r] * rl[r];
      *(f32x4*)(out + ((size_t)b * DIM + ct * 16 + lr) * NTOK + i0 + w * 16 + lg * 4) = o;
    }
  } else {
    float* op = Op + (size_t)blockIdx.x * 4096;   // [c:64][i:64]
    #pragma unroll
    for (int ct = 0; ct < 4; ct++)
      *(f32x4*)(op + (ct * 16 + lr) * 64 + w * 16 + lg * 4) = accO[ct];
    if (lr == 0) {
      #pragma unroll
      for (int r = 0; r < 4; r++) {
        int i = w * 16 + lg * 4 + r;
        Ml[(size_t)blockIdx.x * 128 + i * 2]     = m[r];
        Ml[(size_t)blockIdx.x * 128 + i * 2 + 1] = ls[r];
      }
    }
  }
}

// ---------------- combine: merge nsplit partials per (b, i-block) ----------------
// grid = NB*64, block 256. out[b][c][i] = sum_s O_s[c][i]*exp(m_s-M) / sum_s l_s*exp(m_s-M)
__global__ __launch_bounds__(256) void attn_combine(
    const float* __restrict__ Op, const float* __restrict__ Ml,
    float* __restrict__ out, int nsplit)
{
  __shared__ float wls[64 * 8];    // [i][s] -> exp(m_s - M)/L (normalized weight)
  const int tid = threadIdx.x;
  const int b  = blockIdx.x >> 6;
  const int i0 = (blockIdx.x & 63) << 6;

  __shared__ float mlds[2][64 * 8];
  for (int u = tid; u < 64 * nsplit; u += 256) {
    int i = u / nsplit, s2 = u % nsplit;
    size_t base = ((size_t)blockIdx.x * nsplit + s2) * 128 + i * 2;
    mlds[0][i * 8 + s2] = Ml[base];
    mlds[1][i * 8 + s2] = Ml[base + 1];
  }
  __syncthreads();
  if (tid < 64) {
    float M = -3.0e38f;
    for (int s2 = 0; s2 < nsplit; s2++) M = fmaxf(M, mlds[0][tid * 8 + s2]);
    float L = 0.f;
    for (int s2 = 0; s2 < nsplit; s2++) L += mlds[1][tid * 8 + s2] * __expf(mlds[0][tid * 8 + s2] - M);
    float rL = 1.0f / L;
    for (int s2 = 0; s2 < nsplit; s2++) wls[tid * 8 + s2] = __expf(mlds[0][tid * 8 + s2] - M) * rL;
  }
  __syncthreads();

  for (int k4 = 0; k4 < 4; k4++) {
    int idx = k4 * 256 + tid;
    int c = idx >> 4, i = (idx & 15) * 4;
    f32x4 acc = {0.f, 0.f, 0.f, 0.f};
    for (int s2 = 0; s2 < nsplit; s2++) {
      f32x4 o = *(const f32x4*)(Op + ((size_t)blockIdx.x * nsplit + s2) * 4096 + c * 64 + i);
      #pragma unroll
      for (int r = 0; r < 4; r++)
        acc[r] += o[r] * wls[(i + r) * 8 + s2];
    }
    *(f32x4*)(out + ((size_t)b * DIM + c) * NTOK + i0 + i) = acc;
  }
}

extern "C" void kernel_launch(void* const* d_in, const int* in_sizes, int n_in,
                              void* d_out, int out_size, void* d_ws, size_t ws_size,
                              hipStream_t stream) {
  (void)in_sizes; (void)n_in; (void)out_size;
  const float* x  = (const float*)d_in[0];
  // d_in[1] = t  (unused by the reference computation)
  const float* Wq = (const float*)d_in[2];
  const float* bq = (const float*)d_in[3];
  const float* Wk = (const float*)d_in[4];
  const float* bk = (const float*)d_in[5];
  const float* Wv = (const float*)d_in[6];
  const float* bv = (const float*)d_in[7];
  float* out = (float*)d_out;

  unsigned short* Qg = (unsigned short*)d_ws;                 // [4][4096][64] fp16
  unsigned short* Kg = Qg + (size_t)NB * NTOK * DIM;          // [4][4096][64] fp16
  unsigned short* Vg = Kg + (size_t)NB * NTOK * DIM;          // [4][64][4096] fp16
  const size_t qkv_bytes = (size_t)3 * NB * NTOK * DIM * 2;   // 6.29 MB

  // pick largest SPLIT whose partial buffers fit ws (16896 B per split-block)
  int nsplit = 1;
  for (int sp = 8; sp >= 2; sp >>= 1) {
    if (qkv_bytes + (size_t)256 * sp * 16896 <= ws_size) { nsplit = sp; break; }
  }
  const int direct = (qkv_bytes + (size_t)256 * 16896 > ws_size) ? 1 : 0;
  float* Opf = (float*)((char*)d_ws + qkv_bytes);
  float* Mlf = Opf + (size_t)256 * nsplit * 4096;

  qkv_proj<<<NB * (NTOK / 32), 256, 0, stream>>>(x, Wq, bq, Wk, bk, Wv, bv, Qg, Kg, Vg);
  attn_part<<<NB * 64 * nsplit, 256, 0, stream>>>(Qg, Kg, Vg, Opf, Mlf, out,
                                                  nsplit, 64 / nsplit, direct);
  if (!direct)
    attn_combine<<<NB * 64, 256, 0, stream>>>(Opf, Mlf, out, nsplit);
}